// Round 1
// baseline (1849.590 us; speedup 1.0000x reference)
//
#include <hip/hip_runtime.h>
#include <cmath>

// WRGCN: 2-layer weighted relational GCN.
// N=100000 nodes, E=3200000 edges, R=8 relations, F_IN=128, DIMS=64, C=40.

#define RELS 8

// ---------------------------------------------------------------------------
// GEMM: out[n][0:64] = X[n][0:128] @ W[128][64] (+ bias)
// Block: 256 threads, 64 nodes x 64 dims tile, 4x4 register tile per thread.
// LDS: xsT[f][node] (transposed, padded) + ws[f][d]. K chunked 2x64.
// ---------------------------------------------------------------------------
__global__ __launch_bounds__(256) void gemm_f128_d64(
    const float* __restrict__ X, const float* __restrict__ W,
    const float* __restrict__ bias, float* __restrict__ out, int nN)
{
    __shared__ float xsT[64][65];   // [k][node], padded: conflict-free reads
    __shared__ float ws[64][64];    // [k][d]
    const int tid  = threadIdx.x;
    const int n0   = blockIdx.x * 64;
    const int nmax = nN - n0;       // valid rows in this tile (may be < 64)
    const int tn   = (tid >> 4) * 4;  // node base within tile (0..60)
    const int td   = (tid & 15) * 4;  // dim base within tile (0..60)

    float acc[4][4] = {{0.f,0.f,0.f,0.f},{0.f,0.f,0.f,0.f},
                       {0.f,0.f,0.f,0.f},{0.f,0.f,0.f,0.f}};

    for (int k0 = 0; k0 < 128; k0 += 64) {
        // stage X chunk (64 nodes x 64 k), transposed into LDS
        for (int i = tid; i < 1024; i += 256) {
            int r  = i >> 4;
            int c4 = (i & 15) * 4;
            float4 v = make_float4(0.f, 0.f, 0.f, 0.f);
            if (r < nmax)
                v = *(const float4*)(X + (size_t)(n0 + r) * 128 + k0 + c4);
            xsT[c4 + 0][r] = v.x;
            xsT[c4 + 1][r] = v.y;
            xsT[c4 + 2][r] = v.z;
            xsT[c4 + 3][r] = v.w;
        }
        // stage W chunk (64 k x 64 d)
        for (int i = tid; i < 1024; i += 256) {
            int f  = i >> 4;
            int d4 = (i & 15) * 4;
            *(float4*)&ws[f][d4] = *(const float4*)(W + (size_t)(k0 + f) * 64 + d4);
        }
        __syncthreads();

        #pragma unroll 8
        for (int f = 0; f < 64; ++f) {
            float xv[4], wv[4];
            #pragma unroll
            for (int i = 0; i < 4; ++i) xv[i] = xsT[f][tn + i];
            #pragma unroll
            for (int j = 0; j < 4; ++j) wv[j] = ws[f][td + j];
            #pragma unroll
            for (int i = 0; i < 4; ++i)
                #pragma unroll
                for (int j = 0; j < 4; ++j)
                    acc[i][j] = fmaf(xv[i], wv[j], acc[i][j]);
        }
        __syncthreads();
    }

    float bv[4] = {0.f, 0.f, 0.f, 0.f};
    if (bias) {
        #pragma unroll
        for (int j = 0; j < 4; ++j) bv[j] = bias[td + j];
    }
    #pragma unroll
    for (int i = 0; i < 4; ++i) {
        int n = tn + i;
        if (n < nmax) {
            float4 o;
            o.x = acc[i][0] + bv[0];
            o.y = acc[i][1] + bv[1];
            o.z = acc[i][2] + bv[2];
            o.w = acc[i][3] + bv[3];
            *(float4*)(out + (size_t)(n0 + n) * 64 + td) = o;
        }
    }
}

// ---------------------------------------------------------------------------
// GEMM with fused input ReLU: out[n][0:40] = relu(X[n][0:64]) @ W[64][40] (+b)
// Block: 256 threads, 64 nodes x 40 cols tile; 2x5 register tile per thread.
// ---------------------------------------------------------------------------
__global__ __launch_bounds__(256) void gemm_relu_f64_d40(
    const float* __restrict__ X, const float* __restrict__ W,
    const float* __restrict__ bias, float* __restrict__ out, int nN)
{
    __shared__ float xsT[64][65];   // [k][node]
    __shared__ float ws[64 * 40];   // [k][c] flat
    const int tid  = threadIdx.x;
    const int n0   = blockIdx.x * 64;
    const int nmax = nN - n0;

    for (int i = tid; i < 1024; i += 256) {
        int r  = i >> 4;
        int c4 = (i & 15) * 4;
        float4 v = make_float4(0.f, 0.f, 0.f, 0.f);
        if (r < nmax)
            v = *(const float4*)(X + (size_t)(n0 + r) * 64 + c4);
        xsT[c4 + 0][r] = fmaxf(v.x, 0.f);
        xsT[c4 + 1][r] = fmaxf(v.y, 0.f);
        xsT[c4 + 2][r] = fmaxf(v.z, 0.f);
        xsT[c4 + 3][r] = fmaxf(v.w, 0.f);
    }
    for (int i = tid; i < 640; i += 256)
        ((float4*)ws)[i] = ((const float4*)W)[i];
    __syncthreads();

    const int ng = (tid >> 3) * 2;   // node base (0..62)
    const int cg = (tid & 7) * 5;    // col base  (0..35)
    float acc[2][5] = {{0.f,0.f,0.f,0.f,0.f},{0.f,0.f,0.f,0.f,0.f}};

    #pragma unroll 4
    for (int f = 0; f < 64; ++f) {
        float xv0 = xsT[f][ng];
        float xv1 = xsT[f][ng + 1];
        float wv[5];
        #pragma unroll
        for (int j = 0; j < 5; ++j) wv[j] = ws[f * 40 + cg + j];
        #pragma unroll
        for (int j = 0; j < 5; ++j) {
            acc[0][j] = fmaf(xv0, wv[j], acc[0][j]);
            acc[1][j] = fmaf(xv1, wv[j], acc[1][j]);
        }
    }

    float bv[5] = {0.f, 0.f, 0.f, 0.f, 0.f};
    if (bias) {
        #pragma unroll
        for (int j = 0; j < 5; ++j) bv[j] = bias[cg + j];
    }
    #pragma unroll
    for (int i = 0; i < 2; ++i) {
        int n = ng + i;
        if (n < nmax) {
            #pragma unroll
            for (int j = 0; j < 5; ++j)
                out[(size_t)(n0 + n) * 40 + cg + j] = acc[i][j] + bv[j];
        }
    }
}

// ---------------------------------------------------------------------------
// Edge scatter, DIMS=64: agg[dst] += w * h_sel[src]   (64 floats per edge)
// rel >= 0: h is a single-relation buffer [N][64]; skip edges of other colors.
// rel <  0: h is [R][N][64]; select slab by edge color.
// ---------------------------------------------------------------------------
__global__ __launch_bounds__(256) void scatter_d64(
    const float* __restrict__ h, const int* __restrict__ src,
    const int* __restrict__ dst, const float* __restrict__ ew,
    const int* __restrict__ ec, float* __restrict__ agg,
    int nE, int nN, int rel)
{
    int gid = blockIdx.x * 256 + threadIdx.x;
    int e = gid >> 6;
    if (e >= nE) return;
    int color = ec[e];
    const float* hb = h;
    if (rel >= 0) {
        if (color != rel) return;
    } else {
        hb = h + (size_t)color * nN * 64;
    }
    int c = gid & 63;
    float v = hb[(size_t)src[e] * 64 + c] * ew[e];
    unsafeAtomicAdd(&agg[(size_t)dst[e] * 64 + c], v);
}

// ---------------------------------------------------------------------------
// Edge scatter, C=40: agg[dst] += w * h_sel[src]   (40 floats per edge)
// ---------------------------------------------------------------------------
__global__ __launch_bounds__(256) void scatter_d40(
    const float* __restrict__ h, const int* __restrict__ src,
    const int* __restrict__ dst, const float* __restrict__ ew,
    const int* __restrict__ ec, float* __restrict__ agg,
    int nE, int nN, int rel)
{
    int gid = blockIdx.x * 256 + threadIdx.x;
    if (gid >= nE * 40) return;
    int e = gid / 40;           // magic-mul div by constant
    int c = gid - e * 40;
    int color = ec[e];
    const float* hb = h;
    if (rel >= 0) {
        if (color != rel) return;
    } else {
        hb = h + (size_t)color * nN * 40;
    }
    float v = hb[(size_t)src[e] * 40 + c] * ew[e];
    unsafeAtomicAdd(&agg[(size_t)dst[e] * 40 + c], v);
}

// ---------------------------------------------------------------------------
// Epilogue: per node, write log_softmax(out) to d_out[0:N*40] and raw out to
// d_out[N*40:2*N*40]. One wave (64 lanes) per node, 40 active lanes.
// ---------------------------------------------------------------------------
__global__ __launch_bounds__(256) void logsoftmax_out(
    const float* __restrict__ agg2, float* __restrict__ out, int nN)
{
    int w    = (blockIdx.x * 256 + threadIdx.x) >> 6;
    int lane = threadIdx.x & 63;
    if (w >= nN) return;
    float v = -INFINITY;
    if (lane < 40) v = agg2[(size_t)w * 40 + lane];
    float m = v;
    #pragma unroll
    for (int o = 32; o > 0; o >>= 1) m = fmaxf(m, __shfl_xor(m, o, 64));
    float ex = (lane < 40) ? expf(v - m) : 0.f;
    float s = ex;
    #pragma unroll
    for (int o = 32; o > 0; o >>= 1) s += __shfl_xor(s, o, 64);
    float lse = logf(s) + m;
    if (lane < 40) {
        out[(size_t)w * 40 + lane] = v - lse;
        out[(size_t)nN * 40 + (size_t)w * 40 + lane] = v;
    }
}

// ---------------------------------------------------------------------------
extern "C" void kernel_launch(void* const* d_in, const int* in_sizes, int n_in,
                              void* d_out, int out_size, void* d_ws, size_t ws_size,
                              hipStream_t stream)
{
    const float* x       = (const float*)d_in[0];
    const int*   eidx    = (const int*)  d_in[1];
    const float* ew      = (const float*)d_in[2];
    const int*   ec      = (const int*)  d_in[3];
    const float* W1_rel  = (const float*)d_in[4];
    const float* W1_root = (const float*)d_in[5];
    const float* b1      = (const float*)d_in[6];
    const float* W2_rel  = (const float*)d_in[7];
    const float* W2_root = (const float*)d_in[8];
    const float* b2      = (const float*)d_in[9];

    const int nN = in_sizes[0] / 128;   // 100000
    const int nE = in_sizes[2];         // 3200000
    const int* src = eidx;
    const int* dst = eidx + nE;

    float* wsf = (float*)d_ws;
    const size_t hsz1   = (size_t)nN * 64;   // one relation slab, layer 1
    const size_t aggsz1 = (size_t)nN * 64;
    const size_t aggsz2 = (size_t)nN * 40;

    // Big path: materialize h for all 8 relations (layer1: R*N*64 floats,
    // layer2 reuses the same slab region with R*N*40 floats), single scatter
    // pass per layer. Small path: one relation at a time, 8 scatter passes.
    const size_t need_big = ((size_t)RELS * hsz1 + aggsz1 + aggsz2) * sizeof(float);
    const bool big = (ws_size >= need_big);

    float* h    = wsf;
    float* agg1 = wsf + (big ? (size_t)RELS * hsz1 : hsz1);
    float* agg2 = agg1 + aggsz1;

    const dim3 blk(256);
    const int gemm_blocks = (nN + 63) / 64;
    const int sc64_blocks = (int)(((size_t)nE * 64 + 255) / 256);
    const int sc40_blocks = (int)(((size_t)nE * 40 + 255) / 256);
    const int ls_blocks   = (nN + 3) / 4;

    // ---- Layer 1: agg1 = x@W1_root + b1 ; += scatter(w * (x@W1_rel[c])[src])
    gemm_f128_d64<<<gemm_blocks, blk, 0, stream>>>(x, W1_root, b1, agg1, nN);
    if (big) {
        for (int r = 0; r < RELS; ++r)
            gemm_f128_d64<<<gemm_blocks, blk, 0, stream>>>(
                x, W1_rel + (size_t)r * 128 * 64, nullptr, h + (size_t)r * hsz1, nN);
        scatter_d64<<<sc64_blocks, blk, 0, stream>>>(h, src, dst, ew, ec, agg1, nE, nN, -1);
    } else {
        for (int r = 0; r < RELS; ++r) {
            gemm_f128_d64<<<gemm_blocks, blk, 0, stream>>>(
                x, W1_rel + (size_t)r * 128 * 64, nullptr, h, nN);
            scatter_d64<<<sc64_blocks, blk, 0, stream>>>(h, src, dst, ew, ec, agg1, nE, nN, r);
        }
    }

    // ---- Layer 2: y1 = relu(agg1) fused into GEMM input staging
    gemm_relu_f64_d40<<<gemm_blocks, blk, 0, stream>>>(agg1, W2_root, b2, agg2, nN);
    if (big) {
        for (int r = 0; r < RELS; ++r)
            gemm_relu_f64_d40<<<gemm_blocks, blk, 0, stream>>>(
                agg1, W2_rel + (size_t)r * 64 * 40, nullptr, h + (size_t)r * aggsz2, nN);
        scatter_d40<<<sc40_blocks, blk, 0, stream>>>(h, src, dst, ew, ec, agg2, nE, nN, -1);
    } else {
        for (int r = 0; r < RELS; ++r) {
            gemm_relu_f64_d40<<<gemm_blocks, blk, 0, stream>>>(
                agg1, W2_rel + (size_t)r * 64 * 40, nullptr, h, nN);
            scatter_d40<<<sc40_blocks, blk, 0, stream>>>(h, src, dst, ew, ec, agg2, nE, nN, r);
        }
    }

    // ---- Epilogue: (log_softmax(out), out)
    logsoftmax_out<<<ls_blocks, blk, 0, stream>>>(agg2, (float*)d_out, nN);
}

// Round 2
// 1068.036 us; speedup vs baseline: 1.7318x; 1.7318x over previous
//
#include <hip/hip_runtime.h>
#include <hip/hip_bf16.h>
#include <cmath>

// WRGCN: 2-layer weighted relational GCN.
// N=100000, E=3200000, R=8, F_IN=128, DIMS=64, C=40.
// Strategy: dst-CSR built on device (once, reused by both layers) -> gather
// aggregation with zero float atomics. Per-relation transforms stored bf16.

#define RELS 8

static __device__ __forceinline__ ushort f2bf(float f) {
    __hip_bfloat16 b = __float2bfloat16(f);
    return *reinterpret_cast<ushort*>(&b);
}
static __device__ __forceinline__ float bf2f(ushort u) {
    return __uint_as_float(((unsigned int)u) << 16);
}

// ---------------------------------------------------------------------------
// Root GEMM layer1: out[n][0:64] = X[n][0:128] @ W[128][64] + b   (f32 out)
// ---------------------------------------------------------------------------
__global__ __launch_bounds__(256) void gemm_f128_d64(
    const float* __restrict__ X, const float* __restrict__ W,
    const float* __restrict__ bias, float* __restrict__ out, int nN)
{
    __shared__ float xsT[64][65];
    __shared__ float ws[64][64];
    const int tid  = threadIdx.x;
    const int n0   = blockIdx.x * 64;
    const int nmax = nN - n0;
    const int tn   = (tid >> 4) * 4;
    const int td   = (tid & 15) * 4;

    float acc[4][4] = {{0.f,0.f,0.f,0.f},{0.f,0.f,0.f,0.f},
                       {0.f,0.f,0.f,0.f},{0.f,0.f,0.f,0.f}};

    for (int k0 = 0; k0 < 128; k0 += 64) {
        for (int i = tid; i < 1024; i += 256) {
            int r  = i >> 4;
            int c4 = (i & 15) * 4;
            float4 v = make_float4(0.f, 0.f, 0.f, 0.f);
            if (r < nmax)
                v = *(const float4*)(X + (size_t)(n0 + r) * 128 + k0 + c4);
            xsT[c4 + 0][r] = v.x; xsT[c4 + 1][r] = v.y;
            xsT[c4 + 2][r] = v.z; xsT[c4 + 3][r] = v.w;
        }
        for (int i = tid; i < 1024; i += 256) {
            int f  = i >> 4;
            int d4 = (i & 15) * 4;
            *(float4*)&ws[f][d4] = *(const float4*)(W + (size_t)(k0 + f) * 64 + d4);
        }
        __syncthreads();
        #pragma unroll 8
        for (int f = 0; f < 64; ++f) {
            float xv[4], wv[4];
            #pragma unroll
            for (int i = 0; i < 4; ++i) xv[i] = xsT[f][tn + i];
            #pragma unroll
            for (int j = 0; j < 4; ++j) wv[j] = ws[f][td + j];
            #pragma unroll
            for (int i = 0; i < 4; ++i)
                #pragma unroll
                for (int j = 0; j < 4; ++j)
                    acc[i][j] = fmaf(xv[i], wv[j], acc[i][j]);
        }
        __syncthreads();
    }

    float bv[4];
    #pragma unroll
    for (int j = 0; j < 4; ++j) bv[j] = bias[td + j];
    #pragma unroll
    for (int i = 0; i < 4; ++i) {
        int n = tn + i;
        if (n < nmax) {
            float4 o;
            o.x = acc[i][0] + bv[0]; o.y = acc[i][1] + bv[1];
            o.z = acc[i][2] + bv[2]; o.w = acc[i][3] + bv[3];
            *(float4*)(out + (size_t)(n0 + n) * 64 + td) = o;
        }
    }
}

// ---------------------------------------------------------------------------
// Relation GEMMs layer1 (all 8 in one launch, blockIdx.y = r), bf16 out.
// h[r][n][0:64] = X[n][0:128] @ W1_rel[r]
// ---------------------------------------------------------------------------
__global__ __launch_bounds__(256) void gemm1_rel_bf16(
    const float* __restrict__ X, const float* __restrict__ Wall,
    ushort* __restrict__ hout, int nN)
{
    __shared__ float xsT[64][65];
    __shared__ float ws[64][64];
    const int r = blockIdx.y;
    const float* W = Wall + (size_t)r * 128 * 64;
    ushort* out = hout + (size_t)r * nN * 64;

    const int tid  = threadIdx.x;
    const int n0   = blockIdx.x * 64;
    const int nmax = nN - n0;
    const int tn   = (tid >> 4) * 4;
    const int td   = (tid & 15) * 4;

    float acc[4][4] = {{0.f,0.f,0.f,0.f},{0.f,0.f,0.f,0.f},
                       {0.f,0.f,0.f,0.f},{0.f,0.f,0.f,0.f}};

    for (int k0 = 0; k0 < 128; k0 += 64) {
        for (int i = tid; i < 1024; i += 256) {
            int rr = i >> 4;
            int c4 = (i & 15) * 4;
            float4 v = make_float4(0.f, 0.f, 0.f, 0.f);
            if (rr < nmax)
                v = *(const float4*)(X + (size_t)(n0 + rr) * 128 + k0 + c4);
            xsT[c4 + 0][rr] = v.x; xsT[c4 + 1][rr] = v.y;
            xsT[c4 + 2][rr] = v.z; xsT[c4 + 3][rr] = v.w;
        }
        for (int i = tid; i < 1024; i += 256) {
            int f  = i >> 4;
            int d4 = (i & 15) * 4;
            *(float4*)&ws[f][d4] = *(const float4*)(W + (size_t)(k0 + f) * 64 + d4);
        }
        __syncthreads();
        #pragma unroll 8
        for (int f = 0; f < 64; ++f) {
            float xv[4], wv[4];
            #pragma unroll
            for (int i = 0; i < 4; ++i) xv[i] = xsT[f][tn + i];
            #pragma unroll
            for (int j = 0; j < 4; ++j) wv[j] = ws[f][td + j];
            #pragma unroll
            for (int i = 0; i < 4; ++i)
                #pragma unroll
                for (int j = 0; j < 4; ++j)
                    acc[i][j] = fmaf(xv[i], wv[j], acc[i][j]);
        }
        __syncthreads();
    }

    #pragma unroll
    for (int i = 0; i < 4; ++i) {
        int n = tn + i;
        if (n < nmax) {
            ushort4 o;
            o.x = f2bf(acc[i][0]); o.y = f2bf(acc[i][1]);
            o.z = f2bf(acc[i][2]); o.w = f2bf(acc[i][3]);
            *(ushort4*)(out + (size_t)(n0 + n) * 64 + td) = o;
        }
    }
}

// ---------------------------------------------------------------------------
// Root GEMM layer2: out[n][0:40] = relu(X[n][0:64]) @ W[64][40] + b  (f32 out)
// ---------------------------------------------------------------------------
__global__ __launch_bounds__(256) void gemm_relu_f64_d40(
    const float* __restrict__ X, const float* __restrict__ W,
    const float* __restrict__ bias, float* __restrict__ out, int nN)
{
    __shared__ float xsT[64][65];
    __shared__ float ws[64 * 40];
    const int tid  = threadIdx.x;
    const int n0   = blockIdx.x * 64;
    const int nmax = nN - n0;

    for (int i = tid; i < 1024; i += 256) {
        int r  = i >> 4;
        int c4 = (i & 15) * 4;
        float4 v = make_float4(0.f, 0.f, 0.f, 0.f);
        if (r < nmax)
            v = *(const float4*)(X + (size_t)(n0 + r) * 64 + c4);
        xsT[c4 + 0][r] = fmaxf(v.x, 0.f); xsT[c4 + 1][r] = fmaxf(v.y, 0.f);
        xsT[c4 + 2][r] = fmaxf(v.z, 0.f); xsT[c4 + 3][r] = fmaxf(v.w, 0.f);
    }
    for (int i = tid; i < 640; i += 256)
        ((float4*)ws)[i] = ((const float4*)W)[i];
    __syncthreads();

    const int ng = (tid >> 3) * 2;
    const int cg = (tid & 7) * 5;
    float acc[2][5] = {{0.f,0.f,0.f,0.f,0.f},{0.f,0.f,0.f,0.f,0.f}};

    #pragma unroll 4
    for (int f = 0; f < 64; ++f) {
        float xv0 = xsT[f][ng];
        float xv1 = xsT[f][ng + 1];
        float wv[5];
        #pragma unroll
        for (int j = 0; j < 5; ++j) wv[j] = ws[f * 40 + cg + j];
        #pragma unroll
        for (int j = 0; j < 5; ++j) {
            acc[0][j] = fmaf(xv0, wv[j], acc[0][j]);
            acc[1][j] = fmaf(xv1, wv[j], acc[1][j]);
        }
    }

    float bv[5];
    #pragma unroll
    for (int j = 0; j < 5; ++j) bv[j] = bias[cg + j];
    #pragma unroll
    for (int i = 0; i < 2; ++i) {
        int n = ng + i;
        if (n < nmax)
            #pragma unroll
            for (int j = 0; j < 5; ++j)
                out[(size_t)(n0 + n) * 40 + cg + j] = acc[i][j] + bv[j];
    }
}

// ---------------------------------------------------------------------------
// Relation GEMMs layer2 (blockIdx.y = r), bf16 out, fused input ReLU.
// h2[r][n][0:40] = relu(Xagg[n][0:64]) @ W2_rel[r]
// ---------------------------------------------------------------------------
__global__ __launch_bounds__(256) void gemm2_rel_bf16(
    const float* __restrict__ Xagg, const float* __restrict__ Wall,
    ushort* __restrict__ hout, int nN)
{
    __shared__ float xsT[64][65];
    __shared__ float ws[64 * 40];
    const int r = blockIdx.y;
    const float* W = Wall + (size_t)r * 64 * 40;
    ushort* out = hout + (size_t)r * nN * 40;

    const int tid  = threadIdx.x;
    const int n0   = blockIdx.x * 64;
    const int nmax = nN - n0;

    for (int i = tid; i < 1024; i += 256) {
        int rr = i >> 4;
        int c4 = (i & 15) * 4;
        float4 v = make_float4(0.f, 0.f, 0.f, 0.f);
        if (rr < nmax)
            v = *(const float4*)(Xagg + (size_t)(n0 + rr) * 64 + c4);
        xsT[c4 + 0][rr] = fmaxf(v.x, 0.f); xsT[c4 + 1][rr] = fmaxf(v.y, 0.f);
        xsT[c4 + 2][rr] = fmaxf(v.z, 0.f); xsT[c4 + 3][rr] = fmaxf(v.w, 0.f);
    }
    for (int i = tid; i < 640; i += 256)
        ((float4*)ws)[i] = ((const float4*)W)[i];
    __syncthreads();

    const int ng = (tid >> 3) * 2;
    const int cg = (tid & 7) * 5;
    float acc[2][5] = {{0.f,0.f,0.f,0.f,0.f},{0.f,0.f,0.f,0.f,0.f}};

    #pragma unroll 4
    for (int f = 0; f < 64; ++f) {
        float xv0 = xsT[f][ng];
        float xv1 = xsT[f][ng + 1];
        float wv[5];
        #pragma unroll
        for (int j = 0; j < 5; ++j) wv[j] = ws[f * 40 + cg + j];
        #pragma unroll
        for (int j = 0; j < 5; ++j) {
            acc[0][j] = fmaf(xv0, wv[j], acc[0][j]);
            acc[1][j] = fmaf(xv1, wv[j], acc[1][j]);
        }
    }

    #pragma unroll
    for (int i = 0; i < 2; ++i) {
        int n = ng + i;
        if (n < nmax)
            #pragma unroll
            for (int j = 0; j < 5; ++j)
                out[(size_t)(n0 + n) * 40 + cg + j] = f2bf(acc[i][j]);
    }
}

// ---------------------------------------------------------------------------
// CSR build: histogram -> 3-phase exclusive scan -> cursor fill
// ---------------------------------------------------------------------------
__global__ __launch_bounds__(256) void hist_dst(
    const int* __restrict__ dst, int* __restrict__ counts, int nE)
{
    int e = blockIdx.x * 256 + threadIdx.x;
    if (e < nE) atomicAdd(&counts[dst[e]], 1);
}

__global__ __launch_bounds__(256) void scan_partial(
    const int* __restrict__ counts, int* __restrict__ bsum, int nN)
{
    __shared__ int s[256];
    int t = threadIdx.x;
    int i = blockIdx.x * 256 + t;
    int v = (i < nN) ? counts[i] : 0;
    s[t] = v; __syncthreads();
    for (int o = 1; o < 256; o <<= 1) {
        int u = (t >= o) ? s[t - o] : 0;
        __syncthreads(); s[t] += u; __syncthreads();
    }
    if (t == 255) bsum[blockIdx.x] = s[255];
}

__global__ __launch_bounds__(512) void scan_base(
    const int* __restrict__ bsum, int* __restrict__ bbase, int nb,
    int* __restrict__ row_off, int nN)
{
    __shared__ int s[512];
    int t = threadIdx.x;
    int v = (t < nb) ? bsum[t] : 0;
    s[t] = v; __syncthreads();
    for (int o = 1; o < 512; o <<= 1) {
        int u = (t >= o) ? s[t - o] : 0;
        __syncthreads(); s[t] += u; __syncthreads();
    }
    if (t < nb) bbase[t] = s[t] - v;      // exclusive
    if (t == nb - 1) row_off[nN] = s[t];  // total = E
}

__global__ __launch_bounds__(256) void scan_final(
    const int* __restrict__ counts, const int* __restrict__ bbase,
    int* __restrict__ row_off, int* __restrict__ cursor, int nN)
{
    __shared__ int s[256];
    int t = threadIdx.x;
    int i = blockIdx.x * 256 + t;
    int v = (i < nN) ? counts[i] : 0;
    s[t] = v; __syncthreads();
    for (int o = 1; o < 256; o <<= 1) {
        int u = (t >= o) ? s[t - o] : 0;
        __syncthreads(); s[t] += u; __syncthreads();
    }
    if (i < nN) {
        int off = bbase[blockIdx.x] + s[t] - v;
        row_off[i] = off;
        cursor[i]  = off;
    }
}

__global__ __launch_bounds__(256) void fill_csr(
    const int* __restrict__ src, const int* __restrict__ dst,
    const float* __restrict__ ew, const int* __restrict__ ec,
    int* __restrict__ cursor, unsigned int* __restrict__ pay,
    float* __restrict__ wgt, int nE)
{
    int e = blockIdx.x * 256 + threadIdx.x;
    if (e >= nE) return;
    int p = atomicAdd(&cursor[dst[e]], 1);
    pay[p] = (unsigned int)src[e] | ((unsigned int)ec[e] << 20);
    wgt[p] = ew[e];
}

// ---------------------------------------------------------------------------
// Gather aggregation, DIMS=64: one wave per dst node, lane = output dim.
// agg[n][c] (pre-init with root transform) += sum_e w_e * h[color][src][c]
// ---------------------------------------------------------------------------
__global__ __launch_bounds__(256) void gather_d64(
    const ushort* __restrict__ h, const int* __restrict__ row_off,
    const unsigned int* __restrict__ pay, const float* __restrict__ wgt,
    float* __restrict__ agg, int nN)
{
    int w    = (blockIdx.x * 256 + threadIdx.x) >> 6;
    int lane = threadIdx.x & 63;
    if (w >= nN) return;
    int s0 = row_off[w], s1 = row_off[w + 1];
    float acc = agg[(size_t)w * 64 + lane];
    for (int base = s0; base < s1; base += 64) {
        int m = min(64, s1 - base);
        unsigned int pk = 0; float wv = 0.f;
        if (lane < m) { pk = pay[base + lane]; wv = wgt[base + lane]; }
        for (int j = 0; j < m; ++j) {
            unsigned int pj = __shfl(pk, j, 64);
            float        wj = __shfl(wv, j, 64);
            unsigned int sidx = pj & 0xFFFFFu;
            unsigned int c    = pj >> 20;
            unsigned int hoff = (c * (unsigned int)nN + sidx) * 64u + lane;
            acc = fmaf(wj, bf2f(h[hoff]), acc);
        }
    }
    agg[(size_t)w * 64 + lane] = acc;
}

// ---------------------------------------------------------------------------
// Gather aggregation, C=40: one wave per dst node, lanes 0..39 accumulate.
// ---------------------------------------------------------------------------
__global__ __launch_bounds__(256) void gather_d40(
    const ushort* __restrict__ h, const int* __restrict__ row_off,
    const unsigned int* __restrict__ pay, const float* __restrict__ wgt,
    float* __restrict__ agg, int nN)
{
    int w    = (blockIdx.x * 256 + threadIdx.x) >> 6;
    int lane = threadIdx.x & 63;
    if (w >= nN) return;
    int s0 = row_off[w], s1 = row_off[w + 1];
    float acc = 0.f;
    if (lane < 40) acc = agg[(size_t)w * 40 + lane];
    for (int base = s0; base < s1; base += 64) {
        int m = min(64, s1 - base);
        unsigned int pk = 0; float wv = 0.f;
        if (lane < m) { pk = pay[base + lane]; wv = wgt[base + lane]; }
        for (int j = 0; j < m; ++j) {
            unsigned int pj = __shfl(pk, j, 64);
            float        wj = __shfl(wv, j, 64);
            if (lane < 40) {
                unsigned int sidx = pj & 0xFFFFFu;
                unsigned int c    = pj >> 20;
                unsigned int hoff = (c * (unsigned int)nN + sidx) * 40u + lane;
                acc = fmaf(wj, bf2f(h[hoff]), acc);
            }
        }
    }
    if (lane < 40) agg[(size_t)w * 40 + lane] = acc;
}

// ---------------------------------------------------------------------------
// Epilogue: (log_softmax(out), out)
// ---------------------------------------------------------------------------
__global__ __launch_bounds__(256) void logsoftmax_out(
    const float* __restrict__ agg2, float* __restrict__ out, int nN)
{
    int w    = (blockIdx.x * 256 + threadIdx.x) >> 6;
    int lane = threadIdx.x & 63;
    if (w >= nN) return;
    float v = -INFINITY;
    if (lane < 40) v = agg2[(size_t)w * 40 + lane];
    float m = v;
    #pragma unroll
    for (int o = 32; o > 0; o >>= 1) m = fmaxf(m, __shfl_xor(m, o, 64));
    float ex = (lane < 40) ? expf(v - m) : 0.f;
    float s = ex;
    #pragma unroll
    for (int o = 32; o > 0; o >>= 1) s += __shfl_xor(s, o, 64);
    float lse = logf(s) + m;
    if (lane < 40) {
        out[(size_t)w * 40 + lane] = v - lse;
        out[(size_t)nN * 40 + (size_t)w * 40 + lane] = v;
    }
}

// ---------------------------------------------------------------------------
extern "C" void kernel_launch(void* const* d_in, const int* in_sizes, int n_in,
                              void* d_out, int out_size, void* d_ws, size_t ws_size,
                              hipStream_t stream)
{
    const float* x       = (const float*)d_in[0];
    const int*   eidx    = (const int*)  d_in[1];
    const float* ew      = (const float*)d_in[2];
    const int*   ec      = (const int*)  d_in[3];
    const float* W1_rel  = (const float*)d_in[4];
    const float* W1_root = (const float*)d_in[5];
    const float* b1      = (const float*)d_in[6];
    const float* W2_rel  = (const float*)d_in[7];
    const float* W2_root = (const float*)d_in[8];
    const float* b2      = (const float*)d_in[9];

    const int nN = in_sizes[0] / 128;   // 100000
    const int nE = in_sizes[2];         // 3200000
    const int* src = eidx;
    const int* dst = eidx + nE;

    // workspace layout (bytes); total ~171 MB
    char* w8 = (char*)d_ws;
    size_t off = 0;
    ushort* h = (ushort*)(w8 + off);  off += (size_t)RELS * nN * 64 * sizeof(ushort);
    float* agg1 = (float*)(w8 + off); off += (size_t)nN * 64 * sizeof(float);
    float* agg2 = (float*)(w8 + off); off += (size_t)nN * 40 * sizeof(float);
    int* counts  = (int*)(w8 + off);  off += (size_t)nN * 4;
    int* row_off = (int*)(w8 + off);  off += ((size_t)nN + 1) * 4;
    int* cursor  = (int*)(w8 + off);  off += (size_t)nN * 4;
    int* bsum    = (int*)(w8 + off);  off += 4096;
    int* bbase   = (int*)(w8 + off);  off += 4096;
    unsigned int* pay = (unsigned int*)(w8 + off); off += (size_t)nE * 4;
    float* wgt   = (float*)(w8 + off); off += (size_t)nE * 4;

    const dim3 blk(256);
    const int NB          = (nN + 255) / 256;          // 391 scan blocks (<=512)
    const int gemm_blocks = (nN + 63) / 64;
    const int edge_blocks = (nE + 255) / 256;
    const int wave_blocks = (int)(((size_t)nN * 64 + 255) / 256);
    const int ls_blocks   = (nN + 3) / 4;

    // ---- CSR build (reused by both layers)
    hipMemsetAsync(counts, 0, (size_t)nN * 4, stream);
    hist_dst<<<edge_blocks, blk, 0, stream>>>(dst, counts, nE);
    scan_partial<<<NB, blk, 0, stream>>>(counts, bsum, nN);
    scan_base<<<1, dim3(512), 0, stream>>>(bsum, bbase, NB, row_off, nN);
    scan_final<<<NB, blk, 0, stream>>>(counts, bbase, row_off, cursor, nN);
    fill_csr<<<edge_blocks, blk, 0, stream>>>(src, dst, ew, ec, cursor, pay, wgt, nE);

    // ---- Layer 1
    gemm_f128_d64<<<gemm_blocks, blk, 0, stream>>>(x, W1_root, b1, agg1, nN);
    gemm1_rel_bf16<<<dim3(gemm_blocks, RELS), blk, 0, stream>>>(x, W1_rel, h, nN);
    gather_d64<<<wave_blocks, blk, 0, stream>>>(h, row_off, pay, wgt, agg1, nN);

    // ---- Layer 2 (h buffer reused as [R][N][40] bf16)
    gemm_relu_f64_d40<<<gemm_blocks, blk, 0, stream>>>(agg1, W2_root, b2, agg2, nN);
    gemm2_rel_bf16<<<dim3(gemm_blocks, RELS), blk, 0, stream>>>(agg1, W2_rel, h, nN);
    gather_d40<<<wave_blocks, blk, 0, stream>>>(h, row_off, pay, wgt, agg2, nN);

    // ---- Epilogue
    logsoftmax_out<<<ls_blocks, blk, 0, stream>>>(agg2, (float*)d_out, nN);
}

// Round 3
// 852.944 us; speedup vs baseline: 2.1685x; 1.2522x over previous
//
#include <hip/hip_runtime.h>
#include <hip/hip_bf16.h>
#include <cmath>

// WRGCN: 2-layer weighted relational GCN.
// N=100000, E=3200000, R=8, F_IN=128, DIMS=64, C=40.
// dst-CSR (built once per call, zero float atomics) + bf16-MFMA relation GEMMs.

#define RELS 8

typedef __attribute__((ext_vector_type(8))) short bf16x8;
typedef __attribute__((ext_vector_type(4))) float f32x4;

static __device__ __forceinline__ ushort f2bf(float f) {
    __hip_bfloat16 b = __float2bfloat16(f);
    return *reinterpret_cast<ushort*>(&b);
}
static __device__ __forceinline__ float bf2f(ushort u) {
    return __uint_as_float(((unsigned int)u) << 16);
}

// ---------------------------------------------------------------------------
// Casts / weight prep
// ---------------------------------------------------------------------------
__global__ __launch_bounds__(256) void cast_f32_bf16x4(
    const float* __restrict__ in, ushort* __restrict__ out, int n4)
{
    int i = blockIdx.x * 256 + threadIdx.x;
    if (i >= n4) return;
    float4 v = ((const float4*)in)[i];
    ushort4 o;
    o.x = f2bf(v.x); o.y = f2bf(v.y); o.z = f2bf(v.z); o.w = f2bf(v.w);
    ((ushort4*)out)[i] = o;
}

__global__ __launch_bounds__(256) void cast_relu_bf16x4(
    const float* __restrict__ in, ushort* __restrict__ out, int n4)
{
    int i = blockIdx.x * 256 + threadIdx.x;
    if (i >= n4) return;
    float4 v = ((const float4*)in)[i];
    ushort4 o;
    o.x = f2bf(fmaxf(v.x, 0.f)); o.y = f2bf(fmaxf(v.y, 0.f));
    o.z = f2bf(fmaxf(v.z, 0.f)); o.w = f2bf(fmaxf(v.w, 0.f));
    ((ushort4*)out)[i] = o;
}

// W1_rel [R][128][64] f32 -> w1t [R][64][128] bf16 (transposed per relation)
__global__ __launch_bounds__(256) void conv_w1(
    const float* __restrict__ W, ushort* __restrict__ wt)
{
    int i = blockIdx.x * 256 + threadIdx.x;
    if (i >= RELS * 128 * 64) return;
    int r = i >> 13, k = (i >> 6) & 127, c = i & 63;
    wt[((size_t)r * 64 + c) * 128 + k] = f2bf(W[i]);
}

// W2_rel [R][64][40] f32 -> w2t [R][48][64] bf16 (transposed, zero-pad cols)
__global__ __launch_bounds__(256) void conv_w2(
    const float* __restrict__ W, ushort* __restrict__ wt)
{
    int i = blockIdx.x * 256 + threadIdx.x;
    if (i >= RELS * 48 * 64) return;
    int r = i / (48 * 64), rem = i - r * (48 * 64);
    int c = rem >> 6, k = rem & 63;
    float v = (c < 40) ? W[((size_t)r * 64 + k) * 40 + c] : 0.f;
    wt[i] = f2bf(v);
}

// ---------------------------------------------------------------------------
// Root GEMM layer1: out[n][0:64] = X[n][0:128] @ W[128][64] + b   (f32)
// ---------------------------------------------------------------------------
__global__ __launch_bounds__(256) void gemm_f128_d64(
    const float* __restrict__ X, const float* __restrict__ W,
    const float* __restrict__ bias, float* __restrict__ out, int nN)
{
    __shared__ float xsT[64][65];
    __shared__ float ws[64][64];
    const int tid  = threadIdx.x;
    const int n0   = blockIdx.x * 64;
    const int nmax = nN - n0;
    const int tn   = (tid >> 4) * 4;
    const int td   = (tid & 15) * 4;

    float acc[4][4] = {{0.f,0.f,0.f,0.f},{0.f,0.f,0.f,0.f},
                       {0.f,0.f,0.f,0.f},{0.f,0.f,0.f,0.f}};

    for (int k0 = 0; k0 < 128; k0 += 64) {
        for (int i = tid; i < 1024; i += 256) {
            int r  = i >> 4;
            int c4 = (i & 15) * 4;
            float4 v = make_float4(0.f, 0.f, 0.f, 0.f);
            if (r < nmax)
                v = *(const float4*)(X + (size_t)(n0 + r) * 128 + k0 + c4);
            xsT[c4 + 0][r] = v.x; xsT[c4 + 1][r] = v.y;
            xsT[c4 + 2][r] = v.z; xsT[c4 + 3][r] = v.w;
        }
        for (int i = tid; i < 1024; i += 256) {
            int f  = i >> 4;
            int d4 = (i & 15) * 4;
            *(float4*)&ws[f][d4] = *(const float4*)(W + (size_t)(k0 + f) * 64 + d4);
        }
        __syncthreads();
        #pragma unroll 8
        for (int f = 0; f < 64; ++f) {
            float xv[4], wv[4];
            #pragma unroll
            for (int i = 0; i < 4; ++i) xv[i] = xsT[f][tn + i];
            #pragma unroll
            for (int j = 0; j < 4; ++j) wv[j] = ws[f][td + j];
            #pragma unroll
            for (int i = 0; i < 4; ++i)
                #pragma unroll
                for (int j = 0; j < 4; ++j)
                    acc[i][j] = fmaf(xv[i], wv[j], acc[i][j]);
        }
        __syncthreads();
    }

    float bv[4];
    #pragma unroll
    for (int j = 0; j < 4; ++j) bv[j] = bias[td + j];
    #pragma unroll
    for (int i = 0; i < 4; ++i) {
        int n = tn + i;
        if (n < nmax) {
            float4 o;
            o.x = acc[i][0] + bv[0]; o.y = acc[i][1] + bv[1];
            o.z = acc[i][2] + bv[2]; o.w = acc[i][3] + bv[3];
            *(float4*)(out + (size_t)(n0 + n) * 64 + td) = o;
        }
    }
}

// ---------------------------------------------------------------------------
// Relation GEMMs layer1 (MFMA bf16): h[r][n][0:64] = xb[n][0:128] @ W1[r]
// Block 256 (4 waves), tile 64 rows x 64 cols, K=128.
// LDS xs[64][128] bf16 + wt[64][128] bf16 (W^T), XOR-swizzled rows.
// ---------------------------------------------------------------------------
__global__ __launch_bounds__(256) void gemm1_rel_mfma(
    const ushort* __restrict__ xb, const ushort* __restrict__ w1t,
    ushort* __restrict__ hout, int nN)
{
    __shared__ ushort xs[64 * 128];
    __shared__ ushort wt[64 * 128];
    const int r    = blockIdx.y;
    const int tid  = threadIdx.x;
    const int n0   = blockIdx.x * 64;
    const int nmax = nN - n0;
    ushort* out = hout + (size_t)r * nN * 64;
    const ushort* wsrc = w1t + (size_t)r * 64 * 128;

    // stage x tile: 64 rows x 128 cols bf16, 16B chunks, swizzle byte^=(row&7)<<4
    for (int i = tid; i < 1024; i += 256) {
        int row = i >> 4, ch = i & 15;
        uint4 v = make_uint4(0u, 0u, 0u, 0u);
        if (row < nmax)
            v = *(const uint4*)(xb + (size_t)(n0 + row) * 128 + ch * 8);
        int off = (row * 256 + ch * 16) ^ ((row & 7) << 4);
        *(uint4*)((char*)xs + off) = v;
    }
    // stage W^T tile: 64 cols x 128 k
    for (int i = tid; i < 1024; i += 256) {
        int row = i >> 4, ch = i & 15;
        uint4 v = *(const uint4*)(wsrc + (size_t)row * 128 + ch * 8);
        int off = (row * 256 + ch * 16) ^ ((row & 7) << 4);
        *(uint4*)((char*)wt + off) = v;
    }
    __syncthreads();

    const int wv   = tid >> 6;
    const int lane = tid & 63;
    const int lr   = wv * 16 + (lane & 15);   // A row
    const int kgb  = (lane >> 4) * 8;         // k sub-base within 32-step

    f32x4 acc[4] = {{0.f,0.f,0.f,0.f},{0.f,0.f,0.f,0.f},
                    {0.f,0.f,0.f,0.f},{0.f,0.f,0.f,0.f}};

    #pragma unroll
    for (int ks = 0; ks < 4; ++ks) {
        int kb = (ks * 32 + kgb) * 2;   // byte offset of 16B fragment in row
        int aoff = (lr * 256 + kb) ^ ((lr & 7) << 4);
        bf16x8 a = *(const bf16x8*)((const char*)xs + aoff);
        #pragma unroll
        for (int ct = 0; ct < 4; ++ct) {
            int col = ct * 16 + (lane & 15);
            int boff = (col * 256 + kb) ^ ((col & 7) << 4);
            bf16x8 b = *(const bf16x8*)((const char*)wt + boff);
            acc[ct] = __builtin_amdgcn_mfma_f32_16x16x32_bf16(a, b, acc[ct], 0, 0, 0);
        }
    }

    // C/D: col = lane&15 (within tile), row = (lane>>4)*4 + reg
    #pragma unroll
    for (int ct = 0; ct < 4; ++ct) {
        int col = ct * 16 + (lane & 15);
        #pragma unroll
        for (int reg = 0; reg < 4; ++reg) {
            int row = wv * 16 + (lane >> 4) * 4 + reg;
            if (row < nmax)
                out[(size_t)(n0 + row) * 64 + col] = f2bf(acc[ct][reg]);
        }
    }
}

// ---------------------------------------------------------------------------
// Root GEMM layer2: out[n][0:40] = relu(X[n][0:64]) @ W[64][40] + b  (f32)
// ---------------------------------------------------------------------------
__global__ __launch_bounds__(256) void gemm_relu_f64_d40(
    const float* __restrict__ X, const float* __restrict__ W,
    const float* __restrict__ bias, float* __restrict__ out, int nN)
{
    __shared__ float xsT[64][65];
    __shared__ float ws[64 * 40];
    const int tid  = threadIdx.x;
    const int n0   = blockIdx.x * 64;
    const int nmax = nN - n0;

    for (int i = tid; i < 1024; i += 256) {
        int r  = i >> 4;
        int c4 = (i & 15) * 4;
        float4 v = make_float4(0.f, 0.f, 0.f, 0.f);
        if (r < nmax)
            v = *(const float4*)(X + (size_t)(n0 + r) * 64 + c4);
        xsT[c4 + 0][r] = fmaxf(v.x, 0.f); xsT[c4 + 1][r] = fmaxf(v.y, 0.f);
        xsT[c4 + 2][r] = fmaxf(v.z, 0.f); xsT[c4 + 3][r] = fmaxf(v.w, 0.f);
    }
    for (int i = tid; i < 640; i += 256)
        ((float4*)ws)[i] = ((const float4*)W)[i];
    __syncthreads();

    const int ng = (tid >> 3) * 2;
    const int cg = (tid & 7) * 5;
    float acc[2][5] = {{0.f,0.f,0.f,0.f,0.f},{0.f,0.f,0.f,0.f,0.f}};

    #pragma unroll 4
    for (int f = 0; f < 64; ++f) {
        float xv0 = xsT[f][ng];
        float xv1 = xsT[f][ng + 1];
        float wv[5];
        #pragma unroll
        for (int j = 0; j < 5; ++j) wv[j] = ws[f * 40 + cg + j];
        #pragma unroll
        for (int j = 0; j < 5; ++j) {
            acc[0][j] = fmaf(xv0, wv[j], acc[0][j]);
            acc[1][j] = fmaf(xv1, wv[j], acc[1][j]);
        }
    }

    float bv[5];
    #pragma unroll
    for (int j = 0; j < 5; ++j) bv[j] = bias[cg + j];
    #pragma unroll
    for (int i = 0; i < 2; ++i) {
        int n = ng + i;
        if (n < nmax)
            #pragma unroll
            for (int j = 0; j < 5; ++j)
                out[(size_t)(n0 + n) * 40 + cg + j] = acc[i][j] + bv[j];
    }
}

// ---------------------------------------------------------------------------
// Relation GEMMs layer2 (MFMA bf16): h2[r][n][0:40] = y1b[n][0:64] @ W2[r]
// Tile 64 rows x 48 cols (cols 40..47 are zero-padded weights), K=64.
// ---------------------------------------------------------------------------
__global__ __launch_bounds__(256) void gemm2_rel_mfma(
    const ushort* __restrict__ y1b, const ushort* __restrict__ w2t,
    ushort* __restrict__ hout, int nN)
{
    __shared__ ushort ys[64 * 64];
    __shared__ ushort wt[48 * 64];
    const int r    = blockIdx.y;
    const int tid  = threadIdx.x;
    const int n0   = blockIdx.x * 64;
    const int nmax = nN - n0;
    ushort* out = hout + (size_t)r * nN * 40;
    const ushort* wsrc = w2t + (size_t)r * 48 * 64;

    for (int i = tid; i < 512; i += 256) {
        int row = i >> 3, ch = i & 7;
        uint4 v = make_uint4(0u, 0u, 0u, 0u);
        if (row < nmax)
            v = *(const uint4*)(y1b + (size_t)(n0 + row) * 64 + ch * 8);
        int off = (row * 128 + ch * 16) ^ ((row & 7) << 4);
        *(uint4*)((char*)ys + off) = v;
    }
    for (int i = tid; i < 384; i += 256) {
        int row = i >> 3, ch = i & 7;
        uint4 v = *(const uint4*)(wsrc + (size_t)row * 64 + ch * 8);
        int off = (row * 128 + ch * 16) ^ ((row & 7) << 4);
        *(uint4*)((char*)wt + off) = v;
    }
    __syncthreads();

    const int wv   = tid >> 6;
    const int lane = tid & 63;
    const int lr   = wv * 16 + (lane & 15);
    const int kgb  = (lane >> 4) * 8;

    f32x4 acc[3] = {{0.f,0.f,0.f,0.f},{0.f,0.f,0.f,0.f},{0.f,0.f,0.f,0.f}};

    #pragma unroll
    for (int ks = 0; ks < 2; ++ks) {
        int kb = (ks * 32 + kgb) * 2;
        int aoff = (lr * 128 + kb) ^ ((lr & 7) << 4);
        bf16x8 a = *(const bf16x8*)((const char*)ys + aoff);
        #pragma unroll
        for (int ct = 0; ct < 3; ++ct) {
            int col = ct * 16 + (lane & 15);
            int boff = (col * 128 + kb) ^ ((col & 7) << 4);
            bf16x8 b = *(const bf16x8*)((const char*)wt + boff);
            acc[ct] = __builtin_amdgcn_mfma_f32_16x16x32_bf16(a, b, acc[ct], 0, 0, 0);
        }
    }

    #pragma unroll
    for (int ct = 0; ct < 3; ++ct) {
        int col = ct * 16 + (lane & 15);
        if (col < 40) {
            #pragma unroll
            for (int reg = 0; reg < 4; ++reg) {
                int row = wv * 16 + (lane >> 4) * 4 + reg;
                if (row < nmax)
                    out[(size_t)(n0 + row) * 40 + col] = f2bf(acc[ct][reg]);
            }
        }
    }
}

// ---------------------------------------------------------------------------
// CSR build: histogram -> 3-phase exclusive scan -> cursor fill (packed 8B)
// ---------------------------------------------------------------------------
__global__ __launch_bounds__(256) void hist_dst(
    const int* __restrict__ dst, int* __restrict__ counts, int nE)
{
    int e = blockIdx.x * 256 + threadIdx.x;
    if (e < nE) atomicAdd(&counts[dst[e]], 1);
}

__global__ __launch_bounds__(256) void scan_partial(
    const int* __restrict__ counts, int* __restrict__ bsum, int nN)
{
    __shared__ int s[256];
    int t = threadIdx.x;
    int i = blockIdx.x * 256 + t;
    int v = (i < nN) ? counts[i] : 0;
    s[t] = v; __syncthreads();
    for (int o = 1; o < 256; o <<= 1) {
        int u = (t >= o) ? s[t - o] : 0;
        __syncthreads(); s[t] += u; __syncthreads();
    }
    if (t == 255) bsum[blockIdx.x] = s[255];
}

__global__ __launch_bounds__(512) void scan_base(
    const int* __restrict__ bsum, int* __restrict__ bbase, int nb,
    int* __restrict__ row_off, int nN)
{
    __shared__ int s[512];
    int t = threadIdx.x;
    int v = (t < nb) ? bsum[t] : 0;
    s[t] = v; __syncthreads();
    for (int o = 1; o < 512; o <<= 1) {
        int u = (t >= o) ? s[t - o] : 0;
        __syncthreads(); s[t] += u; __syncthreads();
    }
    if (t < nb) bbase[t] = s[t] - v;
    if (t == nb - 1) row_off[nN] = s[t];
}

__global__ __launch_bounds__(256) void scan_final(
    const int* __restrict__ counts, const int* __restrict__ bbase,
    int* __restrict__ row_off, int* __restrict__ cursor, int nN)
{
    __shared__ int s[256];
    int t = threadIdx.x;
    int i = blockIdx.x * 256 + t;
    int v = (i < nN) ? counts[i] : 0;
    s[t] = v; __syncthreads();
    for (int o = 1; o < 256; o <<= 1) {
        int u = (t >= o) ? s[t - o] : 0;
        __syncthreads(); s[t] += u; __syncthreads();
    }
    if (i < nN) {
        int off = bbase[blockIdx.x] + s[t] - v;
        row_off[i] = off;
        cursor[i]  = off;
    }
}

__global__ __launch_bounds__(256) void fill_csr(
    const int* __restrict__ src, const int* __restrict__ dst,
    const float* __restrict__ ew, const int* __restrict__ ec,
    int* __restrict__ cursor, uint2* __restrict__ epack, int nE)
{
    int e = blockIdx.x * 256 + threadIdx.x;
    if (e >= nE) return;
    int p = atomicAdd(&cursor[dst[e]], 1);
    epack[p] = make_uint2((unsigned int)src[e] | ((unsigned int)ec[e] << 20),
                          __float_as_uint(ew[e]));
}

// ---------------------------------------------------------------------------
// Gather aggregation, DIMS=64: one wave per dst node, lane = output dim.
// ---------------------------------------------------------------------------
__global__ __launch_bounds__(256) void gather_d64(
    const ushort* __restrict__ h, const int* __restrict__ row_off,
    const uint2* __restrict__ epack, float* __restrict__ agg, int nN)
{
    int w    = (blockIdx.x * 256 + threadIdx.x) >> 6;
    int lane = threadIdx.x & 63;
    if (w >= nN) return;
    int s0 = row_off[w], s1 = row_off[w + 1];
    float acc = agg[(size_t)w * 64 + lane];
    for (int base = s0; base < s1; base += 64) {
        int m = min(64, s1 - base);
        unsigned int pk = 0; float wv = 0.f;
        if (lane < m) {
            uint2 pw = epack[base + lane];
            pk = pw.x; wv = __uint_as_float(pw.y);
        }
        for (int j = 0; j < m; ++j) {
            unsigned int pj = __shfl(pk, j, 64);
            float        wj = __shfl(wv, j, 64);
            unsigned int sidx = pj & 0xFFFFFu;
            unsigned int c    = pj >> 20;
            unsigned int hoff = (c * (unsigned int)nN + sidx) * 64u + lane;
            acc = fmaf(wj, bf2f(h[hoff]), acc);
        }
    }
    agg[(size_t)w * 64 + lane] = acc;
}

// ---------------------------------------------------------------------------
// Gather aggregation, C=40: lanes 0..39 accumulate.
// ---------------------------------------------------------------------------
__global__ __launch_bounds__(256) void gather_d40(
    const ushort* __restrict__ h, const int* __restrict__ row_off,
    const uint2* __restrict__ epack, float* __restrict__ agg, int nN)
{
    int w    = (blockIdx.x * 256 + threadIdx.x) >> 6;
    int lane = threadIdx.x & 63;
    if (w >= nN) return;
    int s0 = row_off[w], s1 = row_off[w + 1];
    float acc = 0.f;
    if (lane < 40) acc = agg[(size_t)w * 40 + lane];
    for (int base = s0; base < s1; base += 64) {
        int m = min(64, s1 - base);
        unsigned int pk = 0; float wv = 0.f;
        if (lane < m) {
            uint2 pw = epack[base + lane];
            pk = pw.x; wv = __uint_as_float(pw.y);
        }
        for (int j = 0; j < m; ++j) {
            unsigned int pj = __shfl(pk, j, 64);
            float        wj = __shfl(wv, j, 64);
            if (lane < 40) {
                unsigned int sidx = pj & 0xFFFFFu;
                unsigned int c    = pj >> 20;
                unsigned int hoff = (c * (unsigned int)nN + sidx) * 40u + lane;
                acc = fmaf(wj, bf2f(h[hoff]), acc);
            }
        }
    }
    if (lane < 40) agg[(size_t)w * 40 + lane] = acc;
}

// ---------------------------------------------------------------------------
// Epilogue: (log_softmax(out), out)
// ---------------------------------------------------------------------------
__global__ __launch_bounds__(256) void logsoftmax_out(
    const float* __restrict__ agg2, float* __restrict__ out, int nN)
{
    int w    = (blockIdx.x * 256 + threadIdx.x) >> 6;
    int lane = threadIdx.x & 63;
    if (w >= nN) return;
    float v = -INFINITY;
    if (lane < 40) v = agg2[(size_t)w * 40 + lane];
    float m = v;
    #pragma unroll
    for (int o = 32; o > 0; o >>= 1) m = fmaxf(m, __shfl_xor(m, o, 64));
    float ex = (lane < 40) ? expf(v - m) : 0.f;
    float s = ex;
    #pragma unroll
    for (int o = 32; o > 0; o >>= 1) s += __shfl_xor(s, o, 64);
    float lse = logf(s) + m;
    if (lane < 40) {
        out[(size_t)w * 40 + lane] = v - lse;
        out[(size_t)nN * 40 + (size_t)w * 40 + lane] = v;
    }
}

// ---------------------------------------------------------------------------
extern "C" void kernel_launch(void* const* d_in, const int* in_sizes, int n_in,
                              void* d_out, int out_size, void* d_ws, size_t ws_size,
                              hipStream_t stream)
{
    const float* x       = (const float*)d_in[0];
    const int*   eidx    = (const int*)  d_in[1];
    const float* ew      = (const float*)d_in[2];
    const int*   ec      = (const int*)  d_in[3];
    const float* W1_rel  = (const float*)d_in[4];
    const float* W1_root = (const float*)d_in[5];
    const float* b1      = (const float*)d_in[6];
    const float* W2_rel  = (const float*)d_in[7];
    const float* W2_root = (const float*)d_in[8];
    const float* b2      = (const float*)d_in[9];

    const int nN = in_sizes[0] / 128;   // 100000
    const int nE = in_sizes[2];         // 3200000
    const int* src = eidx;
    const int* dst = eidx + nE;

    // workspace layout (256B-aligned chunks), total ~197 MB
    char* w8 = (char*)d_ws;
    size_t off = 0;
    auto alloc = [&](size_t bytes) {
        void* p = w8 + off;
        off += (bytes + 255) & ~(size_t)255;
        return p;
    };
    ushort* h      = (ushort*)alloc((size_t)RELS * nN * 64 * 2);  // L2 reuses as [R][N][40]
    ushort* xb     = (ushort*)alloc((size_t)nN * 128 * 2);        // reused as y1b
    float*  agg1   = (float*) alloc((size_t)nN * 64 * 4);
    float*  agg2   = (float*) alloc((size_t)nN * 40 * 4);
    int*    counts = (int*)   alloc((size_t)nN * 4);
    int*    row_off= (int*)   alloc(((size_t)nN + 1) * 4);
    int*    cursor = (int*)   alloc((size_t)nN * 4);
    int*    bsum   = (int*)   alloc(4096);
    int*    bbase  = (int*)   alloc(4096);
    uint2*  epack  = (uint2*) alloc((size_t)nE * 8);
    ushort* w1t    = (ushort*)alloc((size_t)RELS * 64 * 128 * 2);
    ushort* w2t    = (ushort*)alloc((size_t)RELS * 48 * 64 * 2);
    ushort* y1b    = xb;   // x bf16 dead after layer-1 rel GEMMs

    const dim3 blk(256);
    const int NB          = (nN + 255) / 256;
    const int gemm_blocks = (nN + 63) / 64;
    const int edge_blocks = (nE + 255) / 256;
    const int wave_blocks = (int)(((size_t)nN * 64 + 255) / 256);
    const int ls_blocks   = (nN + 3) / 4;

    // ---- CSR build (reused by both layers)
    hipMemsetAsync(counts, 0, (size_t)nN * 4, stream);
    hist_dst<<<edge_blocks, blk, 0, stream>>>(dst, counts, nE);
    scan_partial<<<NB, blk, 0, stream>>>(counts, bsum, nN);
    scan_base<<<1, dim3(512), 0, stream>>>(bsum, bbase, NB, row_off, nN);
    scan_final<<<NB, blk, 0, stream>>>(counts, bbase, row_off, cursor, nN);
    fill_csr<<<edge_blocks, blk, 0, stream>>>(src, dst, ew, ec, cursor, epack, nE);

    // ---- weight/input prep (bf16)
    cast_f32_bf16x4<<<(nN * 128 / 4 + 255) / 256, blk, 0, stream>>>(x, xb, nN * 128 / 4);
    conv_w1<<<(RELS * 128 * 64 + 255) / 256, blk, 0, stream>>>(W1_rel, w1t);
    conv_w2<<<(RELS * 48 * 64 + 255) / 256, blk, 0, stream>>>(W2_rel, w2t);

    // ---- Layer 1
    gemm_f128_d64<<<gemm_blocks, blk, 0, stream>>>(x, W1_root, b1, agg1, nN);
    gemm1_rel_mfma<<<dim3(gemm_blocks, RELS), blk, 0, stream>>>(xb, w1t, h, nN);
    gather_d64<<<wave_blocks, blk, 0, stream>>>(h, row_off, epack, agg1, nN);

    // ---- Layer 2
    cast_relu_bf16x4<<<(nN * 64 / 4 + 255) / 256, blk, 0, stream>>>(agg1, y1b, nN * 64 / 4);
    gemm_relu_f64_d40<<<gemm_blocks, blk, 0, stream>>>(agg1, W2_root, b2, agg2, nN);
    gemm2_rel_mfma<<<dim3(gemm_blocks, RELS), blk, 0, stream>>>(y1b, w2t, h, nN);
    gather_d40<<<wave_blocks, blk, 0, stream>>>(h, row_off, epack, agg2, nN);

    // ---- Epilogue
    logsoftmax_out<<<ls_blocks, blk, 0, stream>>>(agg2, (float*)d_out, nN);
}